// Round 10
// baseline (2369.502 us; speedup 1.0000x reference)
//
#include <hip/hip_runtime.h>

namespace {

typedef _Float16 h2 __attribute__((ext_vector_type(2)));

constexpr int KSTEPS = 512;
constexpr int NSTATE = 128;
constexpr int NINPUT = 32;
constexpr int HID    = 256;
constexpr int FANIN  = 161;
constexpr int BATCH  = 64;
constexpr int CHUNK  = 64;    // k4 time-chunk
constexpr int NCH    = 8;

// ---- workspace layout (bytes) ----
constexpr size_t WS_M  = 0;                                   // 256x256 f16 (M = W1y*W2)
constexpr size_t WS_C  = WS_M + (size_t)HID * HID * 2;        // 256 f32    (c = W1y*b2)
constexpr size_t WS_US = WS_C + HID * 4;                      // B*K*32 f16
constexpr size_t WS_HB = WS_US + (size_t)BATCH * KSTEPS * NINPUT * 2;   // B*K*256 f16
constexpr size_t WS_T  = WS_HB + (size_t)BATCH * KSTEPS * HID * 2;      // B*8*256 f32
// total ~19.9 MB

__device__ __forceinline__ float fdot2(h2 a, h2 b, float c) {
#if __has_builtin(__builtin_amdgcn_fdot2)
  return __builtin_amdgcn_fdot2(a, b, c, false);
#else
  return c + (float)a[0] * (float)b[0] + (float)a[1] * (float)b[1];
#endif
}

__device__ __forceinline__ float fast_tanh(float x) {
  float e2 = __expf(2.0f * x);
  return 1.0f - 2.0f / (e2 + 1.0f);
}

template <int CTRL>
__device__ __forceinline__ float dpp_add(float x) {
  int y = __builtin_amdgcn_update_dpp(0, __float_as_int(x), CTRL, 0xF, 0xF, false);
  return x + __int_as_float(y);
}
// sum across 16 consecutive lanes (4-step DPP butterfly)
__device__ __forceinline__ float red16(float x) {
  x = dpp_add<0xB1>(x);    // xor 1
  x = dpp_add<0x4E>(x);    // xor 2
  x = dpp_add<0x141>(x);   // half-row mirror
  x = dpp_add<0x140>(x);   // row mirror
  return x;
}

#define BAR() __asm__ volatile("s_waitcnt lgkmcnt(0)\n\ts_barrier" ::: "memory")

union F4 { float4 f; h2 h[4]; };

// ---------- K1: M = W1y*W2 (f16), c = W1y*b2 (f32) ----------
__global__ __launch_bounds__(256)
void k1_compose(const float* __restrict__ W1, const float* __restrict__ W2,
                const float* __restrict__ b2, _Float16* __restrict__ wsM,
                float* __restrict__ wsC) {
  const int j  = blockIdx.x;
  const int hc = threadIdx.x;
  const float* w1row = W1 + (size_t)j * FANIN + 1;
  float acc = 0.0f;
  for (int o = 0; o < NSTATE; ++o)
    acc = __builtin_fmaf(w1row[o], W2[(size_t)o * HID + hc], acc);
  wsM[(size_t)j * HID + hc] = (_Float16)acc;
  if (hc == 0) {
    float ca = 0.0f;
    for (int o = 0; o < NSTATE; ++o) ca = __builtin_fmaf(w1row[o], b2[o], ca);
    wsC[j] = ca;
  }
}

// ---------- K1b: transcode us (f32 -> f16) ----------
__global__ __launch_bounds__(256)
void k1b_transcode(const float* __restrict__ us, _Float16* __restrict__ us16) {
  const size_t idx = ((size_t)blockIdx.x * 256 + threadIdx.x) * 4;
  const float4 v = *(const float4*)(us + idx);
  us16[idx + 0] = (_Float16)v.x;
  us16[idx + 1] = (_Float16)v.y;
  us16[idx + 2] = (_Float16)v.z;
  us16[idx + 3] = (_Float16)v.w;
}

// ---------- K2: h-space recurrence. 64 blocks x 512 thr (2 waves/SIMD). ----------
// Thread (g2=lt>>4 in 0..31, kc=lt&15): M rows 8g2..8g2+7 x cols 16kc..16kc+15
// (w1m = 64 VGPRs -> whole working set fits arch VGPRs, no AGPR copies).
// Owner lanes kc<8 own row j=8g2+kc: combine, tanh, h-write, hB/S accumulation.
// h layout: 16 chunks, stride 24 f16 (48 B: 16B-aligned, 2-way bank alias = free).
// One lgkm-only barrier per stage; u prefetched one step ahead into registers.
__global__ __launch_bounds__(512, 1)
void k2_main(const float* __restrict__ ts,
             const float* __restrict__ y0,
             const float* __restrict__ W1,
             const float* __restrict__ b1,
             char* __restrict__ ws)
{
  const int lt = threadIdx.x;          // 0..511
  const int g2 = lt >> 4;              // 0..31
  const int kc = lt & 15;              // 0..15
  const int b  = blockIdx.x;
  const bool owner = (kc < 8);
  const int jrow = 8 * g2 + kc;        // valid on owner lanes

  const _Float16* wsM  = (const _Float16*)(ws + WS_M);
  const float*    wsC  = (const float*)(ws + WS_C);
  const _Float16* us16 = (const _Float16*)(ws + WS_US) + (size_t)b * KSTEPS * NINPUT;
  _Float16*       wsHB = (_Float16*)(ws + WS_HB) + (size_t)b * KSTEPS * HID;
  float*          wsT  = (float*)(ws + WS_T) + (size_t)b * NCH * HID;

  __shared__ __align__(16) _Float16 hbuf[2][16 * 24];   // stride-24 chunks
  __shared__ __align__(16) float y0s[NSTATE];

  // ---- M chunk: 8 rows x 16 cols = 64 VGPRs ----
  h2 w1m[8][8];
  #pragma unroll
  for (int r = 0; r < 8; ++r) {
    const F4* mp = (const F4*)(wsM + (size_t)(8 * g2 + r) * HID + 16 * kc);
    F4 m0 = mp[0], m1 = mp[1];
    #pragma unroll
    for (int i = 0; i < 4; ++i) { w1m[r][i] = m0.h[i]; w1m[r][4 + i] = m1.h[i]; }
  }

  // ---- owner-row constants ----
  float w1t = 0.0f, cR = 0.0f;
  h2 w1u[16];
  #pragma unroll
  for (int i = 0; i < 16; ++i) w1u[i] = h2{(_Float16)0.0f, (_Float16)0.0f};
  if (owner) {
    const float* row = W1 + (size_t)jrow * FANIN;
    w1t = row[0];
    cR  = wsC[jrow];
    #pragma unroll
    for (int i = 0; i < 16; ++i)
      w1u[i] = h2{(_Float16)row[129 + 2 * i], (_Float16)row[130 + 2 * i]};
  }

  // ---- P = W1y*y0 + b1 (fp32, owner lanes, one-time) ----
  if (lt < NSTATE) y0s[lt] = y0[(size_t)b * NSTATE + lt];
  __syncthreads();
  float P = 0.0f;
  if (owner) {
    P = b1[jrow];
    const float* wy = W1 + (size_t)jrow * FANIN + 1;
    #pragma unroll 8
    for (int o = 0; o < NSTATE; ++o) P = __builtin_fmaf(wy[o], y0s[o], P);
  }

  constexpr double CcD[5] = {0.161, 0.327, 0.9, 0.9800255409045097, 1.0};
  constexpr float Af[5][5] = {
    {0.161f, 0.f, 0.f, 0.f, 0.f},
    {-0.008480655492356989f, 0.335480655492357f, 0.f, 0.f, 0.f},
    {2.8971530571054935f, -6.359448489975075f, 4.3622954328695815f, 0.f, 0.f},
    {5.325864828439257f, -11.748883564062828f, 7.4955393428898365f, -0.09249506636175525f, 0.f},
    {5.86145544294642f, -12.92096931784711f, 8.159367898576159f, -0.071584973281401f,
     -0.028269050394068383f}};
  constexpr float Bf[6] = {0.09646076681806523f, 0.01f, 0.4798896504144996f,
                           1.379008574103742f, -3.290069515436081f, 2.324710524099774f};

  // ---- init: Ua = W1u*u_0 (owner); prefetch u_1 into registers ----
  float Ua = 0.0f, Ub = 0.0f, Uap = 0.0f, D = 0.0f;
  {
    const F4* up = (const F4*)(us16);
    F4 t0 = up[0], t1 = up[1], t2 = up[2], t3 = up[3];
    if (owner) {
      float s = 0.0f;
      #pragma unroll
      for (int q = 0; q < 4; ++q) {
        s = fdot2(w1u[q],      t0.h[q], s);
        s = fdot2(w1u[4 + q],  t1.h[q], s);
        s = fdot2(w1u[8 + q],  t2.h[q], s);
        s = fdot2(w1u[12 + q], t3.h[q], s);
      }
      Ua = s;
    }
  }
  F4 ur0, ur1, ur2, ur3;   // u_{i+1} prefetch
  {
    const F4* up = (const F4*)(us16 + NINPUT);
    ur0 = up[0]; ur1 = up[1]; ur2 = up[2]; ur3 = up[3];
  }

  float tcur = ts[0], tn1 = ts[1], dtp = 1.0f;
  const int slot = owner ? (24 * (jrow >> 4) + (jrow & 15)) : 0;
  float hB = 0.0f, Sacc = 0.0f;
  if (owner) {
    const float h0 = fast_tanh(__builtin_fmaf(w1t, tcur, P + Ua));
    hbuf[0][slot] = (_Float16)h0;
    hB = Bf[0] * h0;
  }
  float aR[6] = {0.f, 0.f, 0.f, 0.f, 0.f, 0.f};

  for (int i = 0; i < KSTEPS - 1; ++i) {
    const float dt = tn1 - tcur;
    const int   i2 = (i + 2 < KSTEPS) ? (i + 2) : (KSTEPS - 1);
    const float tn2 = ts[i2];

    // chunk-offset store for k4 (S at chunk boundary)
    if (owner && i > 0 && (i & (CHUNK - 1)) == 0)
      wsT[(size_t)(i >> 6) * HID + jrow] = Sacc;

    #pragma unroll
    for (int e = 0; e < 6; ++e) {
      BAR();   // h_e ready in hbuf[e&1]

      const F4* hp = (const F4*)(&hbuf[e & 1][24 * kc]);
      F4 hc0 = hp[0], hc1 = hp[1];

      if (e == 5) {
        if (owner) wsHB[(size_t)i * HID + jrow] = (_Float16)hB;  // fire & forget
      }
      if (e == 0 && owner) {
        // Ub = W1u*u_{i+1} from prefetched registers (no global latency)
        float s = 0.0f;
        #pragma unroll
        for (int q = 0; q < 4; ++q) {
          s = fdot2(w1u[q],      ur0.h[q], s);
          s = fdot2(w1u[4 + q],  ur1.h[q], s);
          s = fdot2(w1u[8 + q],  ur2.h[q], s);
          s = fdot2(w1u[12 + q], ur3.h[q], s);
        }
        Ub = s;
        D = (i == 0) ? (Ub - Ua) : (Ua - Uap) * (dt / dtp);
      }
      if (e == 1) {
        // prefetch u_{i+2} (consumed at e==0 of next step)
        const F4* up = (const F4*)(us16 + (size_t)i2 * NINPUT);
        ur0 = up[0]; ur1 = up[1]; ur2 = up[2]; ur3 = up[3];
      }

      // ---- a_e = M*h_e : 8 rows x 8 dot2, 2 chains ----
      float acc[8];
      #pragma unroll
      for (int r = 0; r < 8; ++r) {
        float a0 = fdot2(w1m[r][0], hc0.h[0], 0.0f);
        float a1 = fdot2(w1m[r][1], hc0.h[1], 0.0f);
        a0 = fdot2(w1m[r][2], hc0.h[2], a0);
        a1 = fdot2(w1m[r][3], hc0.h[3], a1);
        a0 = fdot2(w1m[r][4], hc1.h[0], a0);
        a1 = fdot2(w1m[r][5], hc1.h[1], a1);
        a0 = fdot2(w1m[r][6], hc1.h[2], a0);
        a1 = fdot2(w1m[r][7], hc1.h[3], a1);
        acc[r] = a0 + a1;
      }
      #pragma unroll
      for (int r = 0; r < 8; ++r) acc[r] = red16(acc[r]);
      float ae = acc[0];
      #pragma unroll
      for (int r = 1; r < 8; ++r) ae = (kc == r) ? acc[r] : ae;

      if (owner) {
        ae += cR;
        aR[e] = ae;
        if (e < 5) {
          float acm = 0.0f;
          #pragma unroll
          for (int mm = 0; mm <= e; ++mm) acm = __builtin_fmaf(Af[e][mm], aR[mm], acm);
          const double th = CcD[e];
          const float cu0 = (float)(th * th * th - 2.0 * th * th + 1.0);
          const float cu1 = (float)(2.0 * th * th - th * th * th);
          const float cd0 = (float)(th * th * th - 2.0 * th * th + th);
          const float ut  = cu0 * Ua + cu1 * Ub + cd0 * D;
          const float te  = __builtin_fmaf((float)th, dt, tcur);
          float pre = __builtin_fmaf(dt, acm, P) + ut;
          pre = __builtin_fmaf(w1t, te, pre);
          const float hv = fast_tanh(pre);
          hbuf[(e + 1) & 1][slot] = (_Float16)hv;
          hB = __builtin_fmaf(Bf[e + 1], hv, hB);
        } else {
          float acm = 0.0f;
          #pragma unroll
          for (int mm = 0; mm < 6; ++mm) acm = __builtin_fmaf(Bf[mm], aR[mm], acm);
          P = __builtin_fmaf(dt, acm, P);
          Sacc = __builtin_fmaf(dt, hB, Sacc);
          float pre = __builtin_fmaf(w1t, tn1, P + Ub);   // u(0) next step = u_{i+1}
          const float hv = fast_tanh(pre);
          hbuf[0][slot] = (_Float16)hv;
          hB = Bf[0] * hv;
        }
      }
    }

    Uap = Ua; Ua = Ub;
    dtp = dt; tcur = tn1; tn1 = tn2;
  }
}

// ---------- K4: out[b][i+1] = y0 + W2*S_i, time-chunk parallel (512 blocks) ----------
__global__ __launch_bounds__(256, 1)
void k4_out(const float* __restrict__ ts,
            const float* __restrict__ y0,
            const float* __restrict__ W2,
            const char* __restrict__ ws,
            float* __restrict__ out)
{
  const int blk = blockIdx.x;
  const int b = blk >> 3;
  const int c = blk & 7;
  const int lt = threadIdx.x;
  const int o    = lt >> 1;
  const int half = lt & 1;

  const _Float16* wsHB = (const _Float16*)(ws + WS_HB) + (size_t)b * KSTEPS * HID;
  const float*    wsT  = (const float*)(ws + WS_T) + (size_t)b * NCH * HID;
  float* outb = out + (size_t)b * KSTEPS * NSTATE;

  __shared__ __align__(16) _Float16 Sb[HID];

  h2 w2r[64];
  {
    const float* row = W2 + (size_t)o * HID + 128 * half;
    #pragma unroll
    for (int i = 0; i < 64; ++i)
      w2r[i] = h2{(_Float16)row[2 * i], (_Float16)row[2 * i + 1]};
  }
  const float y0o = y0[(size_t)b * NSTATE + o];
  if (c == 0 && lt < NSTATE) outb[lt] = y0[(size_t)b * NSTATE + lt];

  float S = (c > 0) ? wsT[(size_t)c * HID + lt] : 0.0f;
  const int i0 = c * CHUNK;
  const int n  = (KSTEPS - 1 - i0 < CHUNK) ? (KSTEPS - 1 - i0) : CHUNK;

  float tc = ts[i0], tn = ts[i0 + 1];
  float hcur = (float)wsHB[(size_t)i0 * HID + lt];
  for (int l = 0; l < n; ++l) {
    const int i = i0 + l;
    const int inx = (i + 1 < KSTEPS - 1) ? (i + 1) : (KSTEPS - 2);
    const float hnext = (float)wsHB[(size_t)inx * HID + lt];
    const float tnn = ts[(i + 2 < KSTEPS) ? (i + 2) : (KSTEPS - 1)];

    const float dt = tn - tc;
    S = __builtin_fmaf(dt, hcur, S);
    Sb[lt] = (_Float16)S;
    __syncthreads();

    const F4* sp = (const F4*)(&Sb[128 * half]);
    float v0 = 0.0f, v1 = 0.0f;
    #pragma unroll
    for (int q = 0; q < 16; ++q) {
      F4 sc = sp[q];
      v0 = fdot2(w2r[4 * q + 0], sc.h[0], v0);
      v1 = fdot2(w2r[4 * q + 1], sc.h[1], v1);
      v0 = fdot2(w2r[4 * q + 2], sc.h[2], v0);
      v1 = fdot2(w2r[4 * q + 3], sc.h[3], v1);
    }
    float v = v0 + v1;
    v += __shfl_xor(v, 1);
    if (half == 0) outb[(size_t)(i + 1) * NSTATE + o] = y0o + v;
    __syncthreads();

    hcur = hnext; tc = tn; tn = tnn;
  }
}

} // namespace

extern "C" void kernel_launch(void* const* d_in, const int* in_sizes, int n_in,
                              void* d_out, int out_size, void* d_ws, size_t ws_size,
                              hipStream_t stream) {
  const float* ts = (const float*)d_in[0];
  const float* y0 = (const float*)d_in[1];
  const float* us = (const float*)d_in[2];
  const float* W1 = (const float*)d_in[3];
  const float* b1 = (const float*)d_in[4];
  const float* W2 = (const float*)d_in[5];
  const float* b2 = (const float*)d_in[6];
  float* out = (float*)d_out;
  char* ws = (char*)d_ws;

  _Float16* wsM  = (_Float16*)(ws + WS_M);
  float*    wsC  = (float*)(ws + WS_C);
  _Float16* us16 = (_Float16*)(ws + WS_US);

  hipLaunchKernelGGL(k1_compose, dim3(HID), dim3(HID), 0, stream, W1, W2, b2, wsM, wsC);
  hipLaunchKernelGGL(k1b_transcode, dim3(BATCH * KSTEPS * NINPUT / 1024), dim3(256),
                     0, stream, us, us16);
  hipLaunchKernelGGL(k2_main, dim3(BATCH), dim3(512), 0, stream, ts, y0, W1, b1, ws);
  hipLaunchKernelGGL(k4_out, dim3(BATCH * NCH), dim3(256), 0, stream, ts, y0, W2,
                     (const char*)ws, out);
}

// Round 11
// 1681.862 us; speedup vs baseline: 1.4089x; 1.4089x over previous
//
#include <hip/hip_runtime.h>

namespace {

typedef _Float16 h2 __attribute__((ext_vector_type(2)));

constexpr int KSTEPS = 512;
constexpr int NSTATE = 128;
constexpr int NINPUT = 32;
constexpr int HID    = 256;
constexpr int FANIN  = 161;
constexpr int BATCH  = 64;
constexpr int CHUNK  = 64;    // k4 time-chunk
constexpr int NCH    = 8;

// ---- workspace layout (bytes) ----
constexpr size_t WS_M  = 0;                                   // 256x256 f16 (M = W1y*W2)
constexpr size_t WS_C  = WS_M + (size_t)HID * HID * 2;        // 256 f32    (c = W1y*b2)
constexpr size_t WS_US = WS_C + HID * 4;                      // B*K*32 f16
constexpr size_t WS_HB = WS_US + (size_t)BATCH * KSTEPS * NINPUT * 2;   // B*K*256 f16
constexpr size_t WS_T  = WS_HB + (size_t)BATCH * KSTEPS * HID * 2;      // B*8*256 f32
// total ~19.9 MB (R10 ran with this footprint -> ws_size is sufficient)

__device__ __forceinline__ float fdot2(h2 a, h2 b, float c) {
#if __has_builtin(__builtin_amdgcn_fdot2)
  return __builtin_amdgcn_fdot2(a, b, c, false);
#else
  return c + (float)a[0] * (float)b[0] + (float)a[1] * (float)b[1];
#endif
}

__device__ __forceinline__ float fast_tanh(float x) {
  float e2 = __expf(2.0f * x);
  return 1.0f - 2.0f / (e2 + 1.0f);
}

template <int CTRL>
__device__ __forceinline__ float dpp_add(float x) {
  int y = __builtin_amdgcn_update_dpp(0, __float_as_int(x), CTRL, 0xF, 0xF, false);
  return x + __int_as_float(y);
}
// sum across 8 consecutive lanes (3-step DPP butterfly, VALU pipe only)
__device__ __forceinline__ float red8(float x) {
  x = dpp_add<0xB1>(x);    // xor 1
  x = dpp_add<0x4E>(x);    // xor 2
  x = dpp_add<0x141>(x);   // half-row mirror
  return x;
}

#define BAR() __asm__ volatile("s_waitcnt lgkmcnt(0)\n\ts_barrier" ::: "memory")

union F4 { float4 f; h2 h[4]; };

// ---------- K1: M = W1y*W2 (f16), c = W1y*b2 (f32) ----------
__global__ __launch_bounds__(256)
void k1_compose(const float* __restrict__ W1, const float* __restrict__ W2,
                const float* __restrict__ b2, _Float16* __restrict__ wsM,
                float* __restrict__ wsC) {
  const int j  = blockIdx.x;
  const int hc = threadIdx.x;
  const float* w1row = W1 + (size_t)j * FANIN + 1;
  float acc = 0.0f;
  for (int o = 0; o < NSTATE; ++o)
    acc = __builtin_fmaf(w1row[o], W2[(size_t)o * HID + hc], acc);
  wsM[(size_t)j * HID + hc] = (_Float16)acc;
  if (hc == 0) {
    float ca = 0.0f;
    for (int o = 0; o < NSTATE; ++o) ca = __builtin_fmaf(w1row[o], b2[o], ca);
    wsC[j] = ca;
  }
}

// ---------- K1b: transcode us (f32 -> f16) ----------
__global__ __launch_bounds__(256)
void k1b_transcode(const float* __restrict__ us, _Float16* __restrict__ us16) {
  const size_t idx = ((size_t)blockIdx.x * 256 + threadIdx.x) * 4;
  const float4 v = *(const float4*)(us + idx);
  us16[idx + 0] = (_Float16)v.x;
  us16[idx + 1] = (_Float16)v.y;
  us16[idx + 2] = (_Float16)v.z;
  us16[idx + 3] = (_Float16)v.w;
}

// ---------- K2: h-space recurrence (R9 structure, 256 thr, 1 traj/block) ----------
// Lane lt owns hidden row j = lt. waves_per_eu(1,1) pins occupancy so the
// register allocator keeps the full M-chunk (128 h2) in ARCH VGPRs — no
// AGPR banking / v_accvgpr_read traffic in the hot loop.
__global__ __launch_bounds__(256)
__attribute__((amdgpu_waves_per_eu(1, 1)))
void k2_main(const float* __restrict__ ts,
             const float* __restrict__ y0,
             const float* __restrict__ W1,
             const float* __restrict__ b1,
             char* __restrict__ ws)
{
  const int lt = threadIdx.x;          // 0..255 == owned hidden row
  const int g  = lt >> 3;              // 0..31
  const int kc = lt & 7;               // 0..7
  const int b  = blockIdx.x;

  const _Float16* wsM  = (const _Float16*)(ws + WS_M);
  const float*    wsC  = (const float*)(ws + WS_C);
  const _Float16* us16 = (const _Float16*)(ws + WS_US) + (size_t)b * KSTEPS * NINPUT;
  _Float16*       wsHB = (_Float16*)(ws + WS_HB) + (size_t)b * KSTEPS * HID;
  float*          wsT  = (float*)(ws + WS_T) + (size_t)b * NCH * HID;

  // h double buffer: 8 chunks of 32 f16, stride 40 (80 B: banks 20kc%32 distinct)
  __shared__ __align__(16) _Float16 hbuf[2][320];
  __shared__ __align__(16) float y0s[NSTATE];

  // ---- M chunk into registers: rows 8g..8g+7 x cols 32kc..32kc+31 (128 h2) ----
  h2 w1m[8][16];
  #pragma unroll
  for (int r = 0; r < 8; ++r) {
    const F4* mp = (const F4*)(wsM + (size_t)(8 * g + r) * HID + 32 * kc);
    F4 m0 = mp[0], m1 = mp[1], m2 = mp[2], m3 = mp[3];
    #pragma unroll
    for (int i = 0; i < 4; ++i) {
      w1m[r][i]      = m0.h[i];
      w1m[r][4 + i]  = m1.h[i];
      w1m[r][8 + i]  = m2.h[i];
      w1m[r][12 + i] = m3.h[i];
    }
  }
  // ---- per-owner-row constants ----
  const float* w1row = W1 + (size_t)lt * FANIN;
  const float  w1t   = w1row[0];
  h2 w1u[16];
  #pragma unroll
  for (int i = 0; i < 16; ++i)
    w1u[i] = h2{(_Float16)w1row[129 + 2 * i], (_Float16)w1row[130 + 2 * i]};
  const float cR = wsC[lt];

  // ---- P = W1y*y0 + b1 (fp32) ----
  if (lt < NSTATE) y0s[lt] = y0[(size_t)b * NSTATE + lt];
  __syncthreads();
  float P = b1[lt];
  {
    const float* wy = w1row + 1;
    #pragma unroll 8
    for (int o = 0; o < NSTATE; ++o) P = __builtin_fmaf(wy[o], y0s[o], P);
  }

  constexpr double CcD[5] = {0.161, 0.327, 0.9, 0.9800255409045097, 1.0};
  constexpr float Af[5][5] = {
    {0.161f, 0.f, 0.f, 0.f, 0.f},
    {-0.008480655492356989f, 0.335480655492357f, 0.f, 0.f, 0.f},
    {2.8971530571054935f, -6.359448489975075f, 4.3622954328695815f, 0.f, 0.f},
    {5.325864828439257f, -11.748883564062828f, 7.4955393428898365f, -0.09249506636175525f, 0.f},
    {5.86145544294642f, -12.92096931784711f, 8.159367898576159f, -0.071584973281401f,
     -0.028269050394068383f}};
  constexpr float Bf[6] = {0.09646076681806523f, 0.01f, 0.4798896504144996f,
                           1.379008574103742f, -3.290069515436081f, 2.324710524099774f};

  // ---- init: Ua = W1u*u_0; prefetch u_1 into registers ----
  float Ua, Ub = 0.0f, Uaprev = 0.0f, D = 0.0f;
  {
    const F4* up = (const F4*)(us16);
    F4 u0 = up[0], u1 = up[1], u2 = up[2], u3 = up[3];
    float s = 0.0f;
    #pragma unroll
    for (int i = 0; i < 4; ++i) {
      s = fdot2(w1u[i],      u0.h[i], s);
      s = fdot2(w1u[4 + i],  u1.h[i], s);
      s = fdot2(w1u[8 + i],  u2.h[i], s);
      s = fdot2(w1u[12 + i], u3.h[i], s);
    }
    Ua = s;
  }
  F4 ur0, ur1, ur2, ur3;   // u_{i+1} prefetch
  {
    const F4* up = (const F4*)(us16 + NINPUT);
    ur0 = up[0]; ur1 = up[1]; ur2 = up[2]; ur3 = up[3];
  }

  float tcur = ts[0], tn1 = ts[1];
  float dtp = 1.0f;
  const int slot = 40 * (lt >> 5) + (lt & 31);
  float h0v = fast_tanh(P + Ua + w1t * tcur);
  hbuf[0][slot] = (_Float16)h0v;
  float hB = Bf[0] * h0v;
  float Sacc = 0.0f;
  float aR[6];

  for (int i = 0; i < KSTEPS - 1; ++i) {
    const float dt = tn1 - tcur;
    const int   i2 = (i + 2 < KSTEPS) ? (i + 2) : (KSTEPS - 1);
    const float tn2 = ts[i2];

    // chunk-offset store for the time-parallel out-pass
    if (i > 0 && (i & (CHUNK - 1)) == 0)
      wsT[(size_t)(i >> 6) * HID + lt] = Sacc;

    #pragma unroll
    for (int e = 0; e < 6; ++e) {
      BAR();   // h_e ready in hbuf[e&1]

      const F4* hp = (const F4*)(&hbuf[e & 1][40 * kc]);
      F4 hc0 = hp[0], hc1 = hp[1], hc2 = hp[2], hc3 = hp[3];

      if (e == 5) {
        wsHB[(size_t)i * HID + lt] = (_Float16)hB;   // hB complete: fire & forget
      }
      if (e == 0) {
        // Ub = W1u*u_{i+1} from prefetched registers
        float s = 0.0f;
        #pragma unroll
        for (int q = 0; q < 4; ++q) {
          s = fdot2(w1u[q],      ur0.h[q], s);
          s = fdot2(w1u[4 + q],  ur1.h[q], s);
          s = fdot2(w1u[8 + q],  ur2.h[q], s);
          s = fdot2(w1u[12 + q], ur3.h[q], s);
        }
        Ub = s;
        D = (i == 0) ? (Ub - Ua) : (Ua - Uaprev) * (dt / dtp);
      }
      if (e == 1) {
        // prefetch u_{i+2} (consumed at e==0 of next step)
        const F4* up = (const F4*)(us16 + (size_t)i2 * NINPUT);
        ur0 = up[0]; ur1 = up[1]; ur2 = up[2]; ur3 = up[3];
      }

      // ---- a_e = M*h_e : 8 rows x 16 dot2, 2 chains ----
      float acc[8];
      #pragma unroll
      for (int r = 0; r < 8; ++r) {
        float a0 = fdot2(w1m[r][0], hc0.h[0], 0.0f);
        float a1 = fdot2(w1m[r][1], hc0.h[1], 0.0f);
        a0 = fdot2(w1m[r][2],  hc0.h[2], a0);
        a1 = fdot2(w1m[r][3],  hc0.h[3], a1);
        a0 = fdot2(w1m[r][4],  hc1.h[0], a0);
        a1 = fdot2(w1m[r][5],  hc1.h[1], a1);
        a0 = fdot2(w1m[r][6],  hc1.h[2], a0);
        a1 = fdot2(w1m[r][7],  hc1.h[3], a1);
        a0 = fdot2(w1m[r][8],  hc2.h[0], a0);
        a1 = fdot2(w1m[r][9],  hc2.h[1], a1);
        a0 = fdot2(w1m[r][10], hc2.h[2], a0);
        a1 = fdot2(w1m[r][11], hc2.h[3], a1);
        a0 = fdot2(w1m[r][12], hc3.h[0], a0);
        a1 = fdot2(w1m[r][13], hc3.h[1], a1);
        a0 = fdot2(w1m[r][14], hc3.h[2], a0);
        a1 = fdot2(w1m[r][15], hc3.h[3], a1);
        acc[r] = a0 + a1;
      }
      #pragma unroll
      for (int r = 0; r < 8; ++r) acc[r] = red8(acc[r]);
      float ae = acc[0];
      #pragma unroll
      for (int r = 1; r < 8; ++r) ae = (kc == r) ? acc[r] : ae;
      ae += cR;
      aR[e] = ae;

      if (e < 5) {
        float acm = 0.0f;
        #pragma unroll
        for (int mm = 0; mm <= e; ++mm) acm = __builtin_fmaf(Af[e][mm], aR[mm], acm);
        const double th = CcD[e];
        const float cu0 = (float)(th * th * th - 2.0 * th * th + 1.0);
        const float cu1 = (float)(2.0 * th * th - th * th * th);
        const float cd0 = (float)(th * th * th - 2.0 * th * th + th);
        const float ut  = cu0 * Ua + cu1 * Ub + cd0 * D;
        const float te  = __builtin_fmaf((float)th, dt, tcur);
        float pre = __builtin_fmaf(dt, acm, P) + ut;
        pre = __builtin_fmaf(w1t, te, pre);
        const float hv = fast_tanh(pre);
        hbuf[(e + 1) & 1][slot] = (_Float16)hv;
        hB = __builtin_fmaf(Bf[e + 1], hv, hB);
      } else {
        float acm = 0.0f;
        #pragma unroll
        for (int mm = 0; mm < 6; ++mm) acm = __builtin_fmaf(Bf[mm], aR[mm], acm);
        P = __builtin_fmaf(dt, acm, P);
        Sacc = __builtin_fmaf(dt, hB, Sacc);     // S accumulates BEFORE hB reset
        float pre = P + Ub;                      // u(theta=0) of next step = u_{i+1}
        pre = __builtin_fmaf(w1t, tn1, pre);
        const float hv = fast_tanh(pre);
        hbuf[0][slot] = (_Float16)hv;
        hB = Bf[0] * hv;
      }
    }

    Uaprev = Ua; Ua = Ub;
    dtp = dt; tcur = tn1; tn1 = tn2;
  }
}

// ---------- K4: out[b][i+1] = y0 + W2*S_i, time-chunk parallel (512 blocks) ----------
__global__ __launch_bounds__(256, 1)
void k4_out(const float* __restrict__ ts,
            const float* __restrict__ y0,
            const float* __restrict__ W2,
            const char* __restrict__ ws,
            float* __restrict__ out)
{
  const int blk = blockIdx.x;
  const int b = blk >> 3;
  const int c = blk & 7;
  const int lt = threadIdx.x;
  const int o    = lt >> 1;
  const int half = lt & 1;

  const _Float16* wsHB = (const _Float16*)(ws + WS_HB) + (size_t)b * KSTEPS * HID;
  const float*    wsT  = (const float*)(ws + WS_T) + (size_t)b * NCH * HID;
  float* outb = out + (size_t)b * KSTEPS * NSTATE;

  __shared__ __align__(16) _Float16 Sb[HID];

  h2 w2r[64];
  {
    const float* row = W2 + (size_t)o * HID + 128 * half;
    #pragma unroll
    for (int i = 0; i < 64; ++i)
      w2r[i] = h2{(_Float16)row[2 * i], (_Float16)row[2 * i + 1]};
  }
  const float y0o = y0[(size_t)b * NSTATE + o];
  if (c == 0 && lt < NSTATE) outb[lt] = y0[(size_t)b * NSTATE + lt];

  float S = (c > 0) ? wsT[(size_t)c * HID + lt] : 0.0f;
  const int i0 = c * CHUNK;
  const int n  = (KSTEPS - 1 - i0 < CHUNK) ? (KSTEPS - 1 - i0) : CHUNK;

  float tc = ts[i0], tn = ts[i0 + 1];
  float hcur = (float)wsHB[(size_t)i0 * HID + lt];
  for (int l = 0; l < n; ++l) {
    const int i = i0 + l;
    const int inx = (i + 1 < KSTEPS - 1) ? (i + 1) : (KSTEPS - 2);
    const float hnext = (float)wsHB[(size_t)inx * HID + lt];
    const float tnn = ts[(i + 2 < KSTEPS) ? (i + 2) : (KSTEPS - 1)];

    const float dt = tn - tc;
    S = __builtin_fmaf(dt, hcur, S);
    Sb[lt] = (_Float16)S;
    __syncthreads();

    const F4* sp = (const F4*)(&Sb[128 * half]);
    float v0 = 0.0f, v1 = 0.0f;
    #pragma unroll
    for (int q = 0; q < 16; ++q) {
      F4 sc = sp[q];
      v0 = fdot2(w2r[4 * q + 0], sc.h[0], v0);
      v1 = fdot2(w2r[4 * q + 1], sc.h[1], v1);
      v0 = fdot2(w2r[4 * q + 2], sc.h[2], v0);
      v1 = fdot2(w2r[4 * q + 3], sc.h[3], v1);
    }
    float v = v0 + v1;
    v += __shfl_xor(v, 1);
    if (half == 0) outb[(size_t)(i + 1) * NSTATE + o] = y0o + v;
    __syncthreads();

    hcur = hnext; tc = tn; tn = tnn;
  }
}

} // namespace

extern "C" void kernel_launch(void* const* d_in, const int* in_sizes, int n_in,
                              void* d_out, int out_size, void* d_ws, size_t ws_size,
                              hipStream_t stream) {
  const float* ts = (const float*)d_in[0];
  const float* y0 = (const float*)d_in[1];
  const float* us = (const float*)d_in[2];
  const float* W1 = (const float*)d_in[3];
  const float* b1 = (const float*)d_in[4];
  const float* W2 = (const float*)d_in[5];
  const float* b2 = (const float*)d_in[6];
  float* out = (float*)d_out;
  char* ws = (char*)d_ws;

  _Float16* wsM  = (_Float16*)(ws + WS_M);
  float*    wsC  = (float*)(ws + WS_C);
  _Float16* us16 = (_Float16*)(ws + WS_US);

  hipLaunchKernelGGL(k1_compose, dim3(HID), dim3(HID), 0, stream, W1, W2, b2, wsM, wsC);
  hipLaunchKernelGGL(k1b_transcode, dim3(BATCH * KSTEPS * NINPUT / 1024), dim3(256),
                     0, stream, us, us16);
  hipLaunchKernelGGL(k2_main, dim3(BATCH), dim3(256), 0, stream, ts, y0, W1, b1, ws);
  hipLaunchKernelGGL(k4_out, dim3(BATCH * NCH), dim3(256), 0, stream, ts, y0, W2,
                     (const char*)ws, out);
}